// Round 2
// baseline (720.240 us; speedup 1.0000x reference)
//
#include <hip/hip_runtime.h>
#include <hip/hip_bf16.h>

#define BB 4
#define SS 2048
#define DD 2048
#define HH 16
#define HDD 128

typedef __bf16 bf16x8_t __attribute__((ext_vector_type(8)));
typedef float f32x4 __attribute__((ext_vector_type(4)));

static __device__ __forceinline__ unsigned short f2bf(float f) {
    union { float f; unsigned u; } v; v.f = f;
    unsigned r = v.u + 0x7fffu + ((v.u >> 16) & 1u);
    return (unsigned short)(r >> 16);
}

static __device__ __forceinline__ void gload_lds16(const void* g, void* lds) {
    __builtin_amdgcn_global_load_lds(
        (const __attribute__((address_space(1))) void*)g,
        (__attribute__((address_space(3))) void*)lds, 16, 0, 0);
}

// ---------------- convert x fp32 -> bf16 ----------------
__global__ void convert_x(const float* __restrict__ x, unsigned short* __restrict__ xb, int n) {
    int i = (blockIdx.x * blockDim.x + threadIdx.x) * 4;
    int stride = gridDim.x * blockDim.x * 4;
    for (; i < n; i += stride) {
        float4 v = *(const float4*)(x + i);
        ushort4 o;
        o.x = f2bf(v.x); o.y = f2bf(v.y); o.z = f2bf(v.z); o.w = f2bf(v.w);
        *(ushort4*)(xb + i) = o;
    }
}

// ---------------- transpose + convert weights: T[n][k] = W[k][n] ----------------
__global__ void transpose_w(const float* __restrict__ Wq, const float* __restrict__ Wk,
                            const float* __restrict__ Wv, const float* __restrict__ Wo,
                            unsigned short* __restrict__ WqkvT, unsigned short* __restrict__ WoT) {
    __shared__ float t[32][33];
    const int z = blockIdx.z;
    const float* W = (z == 0) ? Wq : (z == 1) ? Wk : (z == 2) ? Wv : Wo;
    unsigned short* T = (z < 3) ? (WqkvT + (size_t)z * DD * DD) : WoT;
    const int k0 = blockIdx.x * 32, n0 = blockIdx.y * 32;
    const int tx = threadIdx.x, ty = threadIdx.y;
#pragma unroll
    for (int i = 0; i < 4; ++i) {
        int r = ty + i * 8;
        t[r][tx] = W[(size_t)(k0 + r) * DD + n0 + tx];
    }
    __syncthreads();
#pragma unroll
    for (int i = 0; i < 4; ++i) {
        int r = ty + i * 8;
        T[(size_t)(n0 + r) * DD + k0 + tx] = f2bf(t[tx][r]);
    }
}

// ---------------- transpose V [bh][s][hd] -> VT [bh][hd][s] ----------------
__global__ void transpose_v(const unsigned short* __restrict__ V, unsigned short* __restrict__ VT) {
    __shared__ unsigned short t[32][33];
    const int bh = blockIdx.z;
    const int s0 = blockIdx.x * 32, d0 = blockIdx.y * 32;
    const unsigned short* Vb = V + (size_t)bh * SS * HDD;
    unsigned short* Tb = VT + (size_t)bh * HDD * SS;
    const int tx = threadIdx.x, ty = threadIdx.y;
#pragma unroll
    for (int i = 0; i < 4; ++i) {
        int r = ty + i * 8;
        t[r][tx] = Vb[(size_t)(s0 + r) * HDD + d0 + tx];
    }
    __syncthreads();
#pragma unroll
    for (int i = 0; i < 4; ++i) {
        int r = ty + i * 8;
        Tb[(size_t)(d0 + r) * SS + s0 + tx] = t[tx][r];
    }
}

// ---------------- GEMM: C[M][N] = A[M][K] * BT[N][K]^T, bf16 in ----------------
template <int MODE>
__global__ __launch_bounds__(256, 2) void gemm_bt(
    const unsigned short* __restrict__ A, const unsigned short* __restrict__ BT,
    unsigned short* __restrict__ outQ, unsigned short* __restrict__ outK,
    unsigned short* __restrict__ outV, float* __restrict__ outF,
    const float* __restrict__ bias) {
    __shared__ __attribute__((aligned(16))) unsigned short As[2][128 * 32];
    __shared__ __attribute__((aligned(16))) unsigned short Bs[2][128 * 32];
    const int tid = threadIdx.x;
    const int w = tid >> 6, l = tid & 63;
    const int wr = w >> 1, wc = w & 1;
    // XCD-aware bijective swizzle (nwg % 8 == 0 in both uses)
    const int nwg = gridDim.x * gridDim.y;
    int lin = blockIdx.y * gridDim.x + blockIdx.x;
    lin = (lin & 7) * (nwg >> 3) + (lin >> 3);
    const int m0 = (lin / gridDim.x) * 128;
    const int n0 = (lin % gridDim.x) * 128;

    f32x4 acc[4][4] = {};

    auto stage = [&](int buf, int kt) {
        const int k0 = kt * 32;
#pragma unroll
        for (int iss = 0; iss < 2; ++iss) {
            int row = w * 32 + iss * 16 + (l >> 2);
            int kb = (l & 3) * 16;
            const char* ga = (const char*)A + ((size_t)(m0 + row) * DD + k0) * 2 + kb;
            gload_lds16(ga, (char*)&As[buf][0] + (w * 32 + iss * 16) * 64);
            const char* gb = (const char*)BT + ((size_t)(n0 + row) * DD + k0) * 2 + kb;
            gload_lds16(gb, (char*)&Bs[buf][0] + (w * 32 + iss * 16) * 64);
        }
    };

    int cur = 0;
    stage(0, 0);
    __syncthreads();
    const int lrow = l & 15, lko = (l >> 4) * 16;
    for (int t = 0; t < 64; ++t) {
        if (t + 1 < 64) stage(cur ^ 1, t + 1);
        const char* Ab = (const char*)&As[cur][0];
        const char* Bb = (const char*)&Bs[cur][0];
        bf16x8_t af[4], bfg[4];
#pragma unroll
        for (int i = 0; i < 4; ++i)
            af[i] = *(const bf16x8_t*)(Ab + (wr * 64 + i * 16 + lrow) * 64 + lko);
#pragma unroll
        for (int j = 0; j < 4; ++j)
            bfg[j] = *(const bf16x8_t*)(Bb + (wc * 64 + j * 16 + lrow) * 64 + lko);
        __builtin_amdgcn_s_setprio(1);
#pragma unroll
        for (int i = 0; i < 4; ++i)
#pragma unroll
            for (int j = 0; j < 4; ++j)
                acc[i][j] = __builtin_amdgcn_mfma_f32_16x16x32_bf16(af[i], bfg[j], acc[i][j], 0, 0, 0);
        __builtin_amdgcn_s_setprio(0);
        __syncthreads();
        cur ^= 1;
    }

    const int rbase = m0 + wr * 64 + ((l >> 4) << 2);
    const int cbase = n0 + wc * 64 + (l & 15);
    if (MODE == 0) {
#pragma unroll
        for (int j = 0; j < 4; ++j) {
            int col = cbase + j * 16;
            int mat = col >> 11;
            int nn = col & 2047;
            int h = nn >> 7, hd = nn & 127;
            unsigned short* outp = (mat == 0) ? outQ : ((mat == 1) ? outK : outV);
#pragma unroll
            for (int i = 0; i < 4; ++i) {
#pragma unroll
                for (int r = 0; r < 4; ++r) {
                    int row = rbase + i * 16 + r;
                    int b = row >> 11, s = row & 2047;
                    outp[((size_t)(b * HH + h) * SS + s) * HDD + hd] = f2bf(acc[i][j][r]);
                }
            }
        }
    } else {
#pragma unroll
        for (int j = 0; j < 4; ++j) {
            int col = cbase + j * 16;
            float bv = bias[col];
#pragma unroll
            for (int i = 0; i < 4; ++i) {
#pragma unroll
                for (int r = 0; r < 4; ++r) {
                    int row = rbase + i * 16 + r;
                    outF[(size_t)row * DD + col] = acc[i][j][r] + bv;
                }
            }
        }
    }
}

// ---------------- flash attention: 64 q-rows/block, 4 waves, double-buffered K/V ----------------
__global__ __launch_bounds__(256, 2) void attn_kernel(
    const unsigned short* __restrict__ Q, const unsigned short* __restrict__ K,
    const unsigned short* __restrict__ VT, unsigned short* __restrict__ ctx) {
    __shared__ __attribute__((aligned(16))) unsigned short Ks[2][64 * 128];
    __shared__ __attribute__((aligned(16))) unsigned short Vs[2][128 * 64];
    __shared__ __attribute__((aligned(16))) unsigned short Ps[64 * 72];
    const int tid = threadIdx.x, w = tid >> 6, l = tid & 63;
    // reversed qt: heaviest blocks dispatch first (causal load balance)
    const int qt = gridDim.x - 1 - blockIdx.x, h = blockIdx.y, b = blockIdx.z;
    const int bh = b * HH + h;
    const int q0 = qt * 64;
    // scale folded with log2(e): softmax computed in base-2 domain
    const float scale2 = 0.08838834764831845f * 1.4426950408889634f;

    const unsigned short* Qbh = Q + (size_t)bh * SS * HDD;
    const unsigned short* Kbh = K + (size_t)bh * SS * HDD;
    const unsigned short* Vbh = VT + (size_t)bh * HDD * SS;

    const int qrow = q0 + w * 16 + (l & 15);
    bf16x8_t qf[4];
#pragma unroll
    for (int ks = 0; ks < 4; ++ks)
        qf[ks] = *(const bf16x8_t*)(Qbh + (size_t)qrow * HDD + ks * 32 + (l >> 4) * 8);

    // precomputed per-lane staging source bases (pre-swizzled; LDS dest linear)
    const char* kbase[4];
    const char* vbase[4];
#pragma unroll
    for (int iss = 0; iss < 4; ++iss) {
        int p = w * 4096 + iss * 1024 + l * 16;
        int krow = p >> 8, kcb = p & 255;
        kbase[iss] = (const char*)Kbh + (size_t)krow * 256 + (kcb ^ ((krow & 7) << 4));
        int vrow = p >> 7, vcb = p & 127;
        vbase[iss] = (const char*)Vbh + (size_t)vrow * (SS * 2) + (vcb ^ ((vrow & 7) << 4));
    }

    auto stage = [&](int buf, int kv0) {
#pragma unroll
        for (int iss = 0; iss < 4; ++iss)
            gload_lds16(kbase[iss] + (size_t)kv0 * 256, (char*)&Ks[buf][0] + w * 4096 + iss * 1024);
#pragma unroll
        for (int iss = 0; iss < 4; ++iss)
            gload_lds16(vbase[iss] + (size_t)kv0 * 2, (char*)&Vs[buf][0] + w * 4096 + iss * 1024);
    };

    float m_r[4], l_r[4];
#pragma unroll
    for (int r = 0; r < 4; ++r) { m_r[r] = -1e30f; l_r[r] = 0.f; }
    f32x4 o[8] = {};

    int buf = 0;
    stage(0, 0);
    __syncthreads();

    for (int kt = 0; kt <= qt; ++kt) {
        const int kv0 = kt * 64;
        if (kt < qt) stage(buf ^ 1, kv0 + 64);  // prefetch next tile into other buffer

        // S = Q @ K^T  (16x64 per wave)
        const char* Kb = (const char*)&Ks[buf][0];
        const char* Vb = (const char*)&Vs[buf][0];
        f32x4 sf[4] = {};
#pragma unroll
        for (int c = 0; c < 4; ++c) {
            int krow = c * 16 + (l & 15);
            bf16x8_t kb[4];
#pragma unroll
            for (int ks = 0; ks < 4; ++ks) {
                int lb = ks * 64 + (l >> 4) * 16;
                kb[ks] = *(const bf16x8_t*)(Kb + krow * 256 + (lb ^ ((krow & 7) << 4)));
            }
            __builtin_amdgcn_s_setprio(1);
#pragma unroll
            for (int ks = 0; ks < 4; ++ks)
                sf[c] = __builtin_amdgcn_mfma_f32_16x16x32_bf16(qf[ks], kb[ks], sf[c], 0, 0, 0);
            __builtin_amdgcn_s_setprio(0);
        }

        // scale into base-2 domain + causal mask
        const bool diag = (kt == qt);
#pragma unroll
        for (int c = 0; c < 4; ++c) {
#pragma unroll
            for (int r = 0; r < 4; ++r) {
                float v = sf[c][r] * scale2;
                if (diag) {
                    int col = kv0 + c * 16 + (l & 15);
                    int row = q0 + w * 16 + ((l >> 4) << 2) + r;
                    if (col > row) v = -1e30f;
                }
                sf[c][r] = v;
            }
        }
        // row max (k-dim lives across lanes 0..15 of each 16-group)
        float pmax[4];
#pragma unroll
        for (int r = 0; r < 4; ++r) {
            float mx = fmaxf(fmaxf(sf[0][r], sf[1][r]), fmaxf(sf[2][r], sf[3][r]));
#pragma unroll
            for (int off = 1; off < 16; off <<= 1) mx = fmaxf(mx, __shfl_xor(mx, off));
            pmax[r] = mx;
        }
        // defer-max (T13): only rescale when max grew by > 8 (base-2 units)
        bool need = (pmax[0] - m_r[0] > 8.f) || (pmax[1] - m_r[1] > 8.f) ||
                    (pmax[2] - m_r[2] > 8.f) || (pmax[3] - m_r[3] > 8.f);
        if (__any(need)) {
            float alpha[4];
#pragma unroll
            for (int r = 0; r < 4; ++r) {
                float mnew = fmaxf(m_r[r], pmax[r]);
                alpha[r] = exp2f(m_r[r] - mnew);
                m_r[r] = mnew;
                l_r[r] *= alpha[r];
            }
#pragma unroll
            for (int j = 0; j < 8; ++j)
#pragma unroll
                for (int r = 0; r < 4; ++r) o[j][r] *= alpha[r];
        }
        float psum[4] = {0.f, 0.f, 0.f, 0.f};
#pragma unroll
        for (int c = 0; c < 4; ++c) {
#pragma unroll
            for (int r = 0; r < 4; ++r) {
                float p = exp2f(sf[c][r] - m_r[r]);
                psum[r] += p;
                sf[c][r] = p;
            }
        }
#pragma unroll
        for (int r = 0; r < 4; ++r) {
            float s = psum[r];
#pragma unroll
            for (int off = 1; off < 16; off <<= 1) s += __shfl_xor(s, off);
            l_r[r] += s;
        }
        // P -> LDS (wave-private rows, padded stride 72 shorts = 144B)
#pragma unroll
        for (int c = 0; c < 4; ++c)
#pragma unroll
            for (int r = 0; r < 4; ++r) {
                int row = w * 16 + ((l >> 4) << 2) + r;
                Ps[row * 72 + c * 16 + (l & 15)] = f2bf(sf[c][r]);
            }
        // O += P @ V
#pragma unroll
        for (int ks2 = 0; ks2 < 2; ++ks2) {
            bf16x8_t pa = *(const bf16x8_t*)((const char*)Ps + (w * 16 + (l & 15)) * 144 + ks2 * 64 + (l >> 4) * 16);
            __builtin_amdgcn_s_setprio(1);
#pragma unroll
            for (int j = 0; j < 8; ++j) {
                int vrow = j * 16 + (l & 15);
                int lb = ks2 * 64 + (l >> 4) * 16;
                bf16x8_t vb = *(const bf16x8_t*)(Vb + vrow * 128 + (lb ^ ((vrow & 7) << 4)));
                o[j] = __builtin_amdgcn_mfma_f32_16x16x32_bf16(pa, vb, o[j], 0, 0, 0);
            }
            __builtin_amdgcn_s_setprio(0);
        }
        __syncthreads();
        buf ^= 1;
    }

    // epilogue: ctx[b][s][h][hd] bf16
    unsigned short* cb_ = ctx + (size_t)b * SS * DD + (size_t)h * HDD;
#pragma unroll
    for (int r = 0; r < 4; ++r) {
        int row = q0 + w * 16 + ((l >> 4) << 2) + r;
        float inv = 1.f / l_r[r];
#pragma unroll
        for (int j = 0; j < 8; ++j)
            cb_[(size_t)row * DD + j * 16 + (l & 15)] = f2bf(o[j][r] * inv);
    }
}

extern "C" void kernel_launch(void* const* d_in, const int* in_sizes, int n_in,
                              void* d_out, int out_size, void* d_ws, size_t ws_size,
                              hipStream_t stream) {
    (void)in_sizes; (void)n_in; (void)out_size; (void)ws_size;
    const float* x  = (const float*)d_in[0];
    const float* Wq = (const float*)d_in[1];
    const float* Wk = (const float*)d_in[2];
    const float* Wv = (const float*)d_in[3];
    const float* Wo = (const float*)d_in[4];
    const float* bo = (const float*)d_in[5];

    char* ws = (char*)d_ws;
    unsigned short* xb    = (unsigned short*)(ws);
    unsigned short* WqkvT = (unsigned short*)(ws + (32u << 20));
    unsigned short* WoT   = (unsigned short*)(ws + (56u << 20));
    unsigned short* Qb    = (unsigned short*)(ws + (64u << 20));
    unsigned short* Kb    = (unsigned short*)(ws + (96u << 20));
    unsigned short* Vb    = (unsigned short*)(ws + (128u << 20));
    unsigned short* VTb   = (unsigned short*)(ws + (160u << 20));
    unsigned short* ctx   = xb;  // xb dead after QKV GEMM

    convert_x<<<4096, 256, 0, stream>>>(x, xb, BB * SS * DD);
    transpose_w<<<dim3(64, 64, 4), dim3(32, 8), 0, stream>>>(Wq, Wk, Wv, Wo, WqkvT, WoT);
    gemm_bt<0><<<dim3(48, 64), 256, 0, stream>>>(xb, WqkvT, Qb, Kb, Vb, nullptr, nullptr);
    transpose_v<<<dim3(SS / 32, HDD / 32, BB * HH), dim3(32, 8), 0, stream>>>(Vb, VTb);
    attn_kernel<<<dim3(SS / 64, HH, BB), 256, 0, stream>>>(Qb, Kb, VTb, ctx);
    gemm_bt<1><<<dim3(16, 64), 256, 0, stream>>>(ctx, WoT, nullptr, nullptr, nullptr, (float*)d_out, bo);
}

// Round 3
// 592.981 us; speedup vs baseline: 1.2146x; 1.2146x over previous
//
#include <hip/hip_runtime.h>
#include <hip/hip_bf16.h>

#define BB 4
#define SS 2048
#define DD 2048
#define HH 16
#define HDD 128

typedef __bf16 bf16x8_t __attribute__((ext_vector_type(8)));
typedef float f32x4 __attribute__((ext_vector_type(4)));
typedef float f32x16 __attribute__((ext_vector_type(16)));

static __device__ __forceinline__ unsigned short f2bf(float f) {
    union { float f; unsigned u; } v; v.f = f;
    unsigned r = v.u + 0x7fffu + ((v.u >> 16) & 1u);
    return (unsigned short)(r >> 16);
}

static __device__ __forceinline__ unsigned cvtpk_bf16(float lo, float hiv) {
    unsigned r;
    asm("v_cvt_pk_bf16_f32 %0, %1, %2" : "=v"(r) : "v"(lo), "v"(hiv));
    return r;
}

// swap low-32-lane half of a with high-32-lane half of b (in place)
static __device__ __forceinline__ void pl32swap(unsigned& a, unsigned& b) {
    auto rr = __builtin_amdgcn_permlane32_swap((int)a, (int)b, false, false);
    a = (unsigned)rr[0];
    b = (unsigned)rr[1];
}

static __device__ __forceinline__ void gload_lds16(const void* g, void* lds) {
    __builtin_amdgcn_global_load_lds(
        (const __attribute__((address_space(1))) void*)g,
        (__attribute__((address_space(3))) void*)lds, 16, 0, 0);
}

// ---------------- convert x fp32 -> bf16 ----------------
__global__ void convert_x(const float* __restrict__ x, unsigned short* __restrict__ xb, int n) {
    int i = (blockIdx.x * blockDim.x + threadIdx.x) * 4;
    int stride = gridDim.x * blockDim.x * 4;
    for (; i < n; i += stride) {
        float4 v = *(const float4*)(x + i);
        ushort4 o;
        o.x = f2bf(v.x); o.y = f2bf(v.y); o.z = f2bf(v.z); o.w = f2bf(v.w);
        *(ushort4*)(xb + i) = o;
    }
}

// ---------------- transpose + convert weights: T[n][k] = W[k][n] ----------------
__global__ void transpose_w(const float* __restrict__ Wq, const float* __restrict__ Wk,
                            const float* __restrict__ Wv, const float* __restrict__ Wo,
                            unsigned short* __restrict__ WqkvT, unsigned short* __restrict__ WoT) {
    __shared__ float t[32][33];
    const int z = blockIdx.z;
    const float* W = (z == 0) ? Wq : (z == 1) ? Wk : (z == 2) ? Wv : Wo;
    unsigned short* T = (z < 3) ? (WqkvT + (size_t)z * DD * DD) : WoT;
    const int k0 = blockIdx.x * 32, n0 = blockIdx.y * 32;
    const int tx = threadIdx.x, ty = threadIdx.y;
#pragma unroll
    for (int i = 0; i < 4; ++i) {
        int r = ty + i * 8;
        t[r][tx] = W[(size_t)(k0 + r) * DD + n0 + tx];
    }
    __syncthreads();
#pragma unroll
    for (int i = 0; i < 4; ++i) {
        int r = ty + i * 8;
        T[(size_t)(n0 + r) * DD + k0 + tx] = f2bf(t[tx][r]);
    }
}

// ---------------- transpose V [bh][s][hd] -> VT [bh][hd][s] ----------------
__global__ void transpose_v(const unsigned short* __restrict__ V, unsigned short* __restrict__ VT) {
    __shared__ unsigned short t[32][33];
    const int bh = blockIdx.z;
    const int s0 = blockIdx.x * 32, d0 = blockIdx.y * 32;
    const unsigned short* Vb = V + (size_t)bh * SS * HDD;
    unsigned short* Tb = VT + (size_t)bh * HDD * SS;
    const int tx = threadIdx.x, ty = threadIdx.y;
#pragma unroll
    for (int i = 0; i < 4; ++i) {
        int r = ty + i * 8;
        t[r][tx] = Vb[(size_t)(s0 + r) * HDD + d0 + tx];
    }
    __syncthreads();
#pragma unroll
    for (int i = 0; i < 4; ++i) {
        int r = ty + i * 8;
        Tb[(size_t)(d0 + r) * SS + s0 + tx] = t[tx][r];
    }
}

// ---------------- GEMM: C[M][N] = A[M][K] * BT[N][K]^T, bf16 in ----------------
template <int MODE>
__global__ __launch_bounds__(256, 2) void gemm_bt(
    const unsigned short* __restrict__ A, const unsigned short* __restrict__ BT,
    unsigned short* __restrict__ outQ, unsigned short* __restrict__ outK,
    unsigned short* __restrict__ outV, float* __restrict__ outF,
    const float* __restrict__ bias) {
    __shared__ __attribute__((aligned(16))) unsigned short As[2][128 * 32];
    __shared__ __attribute__((aligned(16))) unsigned short Bs[2][128 * 32];
    const int tid = threadIdx.x;
    const int w = tid >> 6, l = tid & 63;
    const int wr = w >> 1, wc = w & 1;
    const int nwg = gridDim.x * gridDim.y;
    int lin = blockIdx.y * gridDim.x + blockIdx.x;
    lin = (lin & 7) * (nwg >> 3) + (lin >> 3);
    const int m0 = (lin / gridDim.x) * 128;
    const int n0 = (lin % gridDim.x) * 128;

    f32x4 acc[4][4] = {};

    auto stage = [&](int buf, int kt) {
        const int k0 = kt * 32;
#pragma unroll
        for (int iss = 0; iss < 2; ++iss) {
            int row = w * 32 + iss * 16 + (l >> 2);
            int kb = (l & 3) * 16;
            const char* ga = (const char*)A + ((size_t)(m0 + row) * DD + k0) * 2 + kb;
            gload_lds16(ga, (char*)&As[buf][0] + (w * 32 + iss * 16) * 64);
            const char* gb = (const char*)BT + ((size_t)(n0 + row) * DD + k0) * 2 + kb;
            gload_lds16(gb, (char*)&Bs[buf][0] + (w * 32 + iss * 16) * 64);
        }
    };

    int cur = 0;
    stage(0, 0);
    __syncthreads();
    const int lrow = l & 15, lko = (l >> 4) * 16;
    for (int t = 0; t < 64; ++t) {
        if (t + 1 < 64) stage(cur ^ 1, t + 1);
        const char* Ab = (const char*)&As[cur][0];
        const char* Bb = (const char*)&Bs[cur][0];
        bf16x8_t af[4], bfg[4];
#pragma unroll
        for (int i = 0; i < 4; ++i)
            af[i] = *(const bf16x8_t*)(Ab + (wr * 64 + i * 16 + lrow) * 64 + lko);
#pragma unroll
        for (int j = 0; j < 4; ++j)
            bfg[j] = *(const bf16x8_t*)(Bb + (wc * 64 + j * 16 + lrow) * 64 + lko);
        __builtin_amdgcn_s_setprio(1);
#pragma unroll
        for (int i = 0; i < 4; ++i)
#pragma unroll
            for (int j = 0; j < 4; ++j)
                acc[i][j] = __builtin_amdgcn_mfma_f32_16x16x32_bf16(af[i], bfg[j], acc[i][j], 0, 0, 0);
        __builtin_amdgcn_s_setprio(0);
        __syncthreads();
        cur ^= 1;
    }

    const int rbase = m0 + wr * 64 + ((l >> 4) << 2);
    const int cbase = n0 + wc * 64 + (l & 15);
    if (MODE == 0) {
#pragma unroll
        for (int j = 0; j < 4; ++j) {
            int col = cbase + j * 16;
            int mat = col >> 11;
            int nn = col & 2047;
            int h = nn >> 7, hd = nn & 127;
            unsigned short* outp = (mat == 0) ? outQ : ((mat == 1) ? outK : outV);
#pragma unroll
            for (int i = 0; i < 4; ++i) {
#pragma unroll
                for (int r = 0; r < 4; ++r) {
                    int row = rbase + i * 16 + r;
                    int b = row >> 11, s = row & 2047;
                    outp[((size_t)(b * HH + h) * SS + s) * HDD + hd] = f2bf(acc[i][j][r]);
                }
            }
        }
    } else {
#pragma unroll
        for (int j = 0; j < 4; ++j) {
            int col = cbase + j * 16;
            float bv = bias[col];
#pragma unroll
            for (int i = 0; i < 4; ++i) {
#pragma unroll
                for (int r = 0; r < 4; ++r) {
                    int row = rbase + i * 16 + r;
                    outF[(size_t)row * DD + col] = acc[i][j][r] + bv;
                }
            }
        }
    }
}

// ---------------- flash attention: 8 warps x 32 q-rows, 32x32 MFMA, swapped QK^T ----------------
// S^T = mfma(K,Q): lane holds q = lane&31, k in regs -> in-register softmax (T12),
// P -> PV A-operand via cvt_pk + permlane32_swap, no P LDS round-trip.
__global__ __launch_bounds__(512, 1) void attn_kernel(
    const unsigned short* __restrict__ Q, const unsigned short* __restrict__ K,
    const unsigned short* __restrict__ VT, unsigned short* __restrict__ ctx) {
    __shared__ __attribute__((aligned(16))) unsigned short Ks[2][64 * 128];  // [k=64][d=128]
    __shared__ __attribute__((aligned(16))) unsigned short Vs[2][128 * 64];  // [d=128][k=64]
    __shared__ float Al[8][32];
    const int tid = threadIdx.x, w = tid >> 6, l = tid & 63;
    const int hi = l >> 5, l31 = l & 31;
    const int hb = hi * 16;
    const int swz = (l31 & 7) << 4;
    const int qt = gridDim.x - 1 - blockIdx.x, h = blockIdx.y, b = blockIdx.z;
    const int bh = b * HH + h;
    const int q0w = qt * 256 + w * 32;
    const int qabs = q0w + l31;
    const int nkv = 4 * qt + 4;
    const float scale2 = 0.08838834764831845f * 1.4426950408889634f;  // scale * log2(e)

    const unsigned short* Qbh = Q + (size_t)bh * SS * HDD;
    const char* Kbh = (const char*)(K + (size_t)bh * SS * HDD);
    const char* Vbh = (const char*)(VT + (size_t)bh * HDD * SS);

    // Q fragments (B-operand): lane holds col q=qabs, kk=hi*8+j within d-slice ds
    bf16x8_t qf[8];
#pragma unroll
    for (int ds = 0; ds < 8; ++ds)
        qf[ds] = *(const bf16x8_t*)(Qbh + (size_t)qabs * HDD + ds * 16 + hi * 8);

    // staging source bases (pre-swizzled; LDS dest linear — both-sides rule)
    const char* kbase[2];
    const char* vbase[2];
#pragma unroll
    for (int iss = 0; iss < 2; ++iss) {
        int p = w * 2048 + iss * 1024 + l * 16;
        int krow = p >> 8, kcb = p & 255;
        kbase[iss] = Kbh + (size_t)krow * 256 + (kcb ^ ((krow & 7) << 4));
        int vrow = p >> 7, vcb = p & 127;
        vbase[iss] = Vbh + (size_t)vrow * (SS * 2) + (vcb ^ ((vrow & 7) << 4));
    }

    auto stage = [&](int buf, int kv0) {
#pragma unroll
        for (int iss = 0; iss < 2; ++iss) {
            gload_lds16(kbase[iss] + (size_t)kv0 * 256, (char*)&Ks[buf][0] + w * 2048 + iss * 1024);
            gload_lds16(vbase[iss] + (size_t)kv0 * 2, (char*)&Vs[buf][0] + w * 2048 + iss * 1024);
        }
    };

    float m_r = -1e30f, l_r = 0.f;
    f32x16 o0 = {}, o1 = {}, o2 = {}, o3 = {};

    int buf = 0;
    stage(0, 0);
    __syncthreads();

    for (int kt = 0; kt < nkv; ++kt) {
        const int kv0 = kt * 64;
        if (kt + 1 < nkv) stage(buf ^ 1, kv0 + 64);

        if (kv0 <= q0w + 31) {  // warp has unmasked work in this tile
            const char* Kb = (const char*)&Ks[buf][0];
            const char* Vb = (const char*)&Vs[buf][0];
            // ---- S^T = K_tile @ Q^T  (rows=k, cols=q) ----
            f32x16 s0 = {}, s1 = {};
            {
                bf16x8_t kf[8];
                const int rb = l31 * 256;
#pragma unroll
                for (int ds = 0; ds < 8; ++ds)
                    kf[ds] = *(const bf16x8_t*)(Kb + rb + ((ds * 32 + hb) ^ swz));
                __builtin_amdgcn_s_setprio(1);
#pragma unroll
                for (int ds = 0; ds < 8; ++ds)
                    s0 = __builtin_amdgcn_mfma_f32_32x32x16_bf16(kf[ds], qf[ds], s0, 0, 0, 0);
                __builtin_amdgcn_s_setprio(0);
#pragma unroll
                for (int ds = 0; ds < 8; ++ds)
                    kf[ds] = *(const bf16x8_t*)(Kb + rb + 32 * 256 + ((ds * 32 + hb) ^ swz));
                __builtin_amdgcn_s_setprio(1);
#pragma unroll
                for (int ds = 0; ds < 8; ++ds)
                    s1 = __builtin_amdgcn_mfma_f32_32x32x16_bf16(kf[ds], qf[ds], s1, 0, 0, 0);
                __builtin_amdgcn_s_setprio(0);
            }

            // ---- scale (+ causal mask) in base-2 domain ----
            if (kv0 + 63 > q0w) {
                const int qrel = qabs - kv0;
#pragma unroll
                for (int r = 0; r < 16; ++r) {
                    const int kl = (r & 3) + 8 * (r >> 2) + 4 * hi;
                    s0[r] = (kl > qrel) ? -1e30f : s0[r] * scale2;
                    s1[r] = (kl + 32 > qrel) ? -1e30f : s1[r] * scale2;
                }
            } else {
#pragma unroll
                for (int r = 0; r < 16; ++r) { s0[r] *= scale2; s1[r] *= scale2; }
            }

            // ---- in-register row max (over 32 own k's) + cross-half swap ----
            float mx = s0[0];
#pragma unroll
            for (int r = 1; r < 16; ++r) mx = fmaxf(mx, s0[r]);
#pragma unroll
            for (int r = 0; r < 16; ++r) mx = fmaxf(mx, s1[r]);
            {
                unsigned mu = __float_as_uint(mx), mu2 = mu;
                pl32swap(mu, mu2);
                mx = fmaxf(__uint_as_float(mu), __uint_as_float(mu2));
            }

            // ---- defer-max (T13): rescale only when max grew > 8 ----
            if (__any(mx - m_r > 8.f)) {
                float mnew = fmaxf(m_r, mx);
                float alpha = exp2f(m_r - mnew);
                m_r = mnew;
                l_r *= alpha;
                Al[w][l31] = alpha;  // lane pair writes same value
#pragma unroll
                for (int r = 0; r < 16; ++r) {
                    float ar = Al[w][(r & 3) + 8 * (r >> 2) + 4 * hi];
                    o0[r] *= ar; o1[r] *= ar; o2[r] *= ar; o3[r] *= ar;
                }
            }

            // ---- P = exp2(S - m), row sum ----
            float ps = 0.f;
#pragma unroll
            for (int r = 0; r < 16; ++r) { s0[r] = exp2f(s0[r] - m_r); ps += s0[r]; }
#pragma unroll
            for (int r = 0; r < 16; ++r) { s1[r] = exp2f(s1[r] - m_r); ps += s1[r]; }
            {
                unsigned pu = __float_as_uint(ps), pu2 = pu;
                pl32swap(pu, pu2);
                l_r += __uint_as_float(pu) + __uint_as_float(pu2);
            }

            // ---- P -> PV A-operand fragments (T12: cvt_pk + permlane32_swap) ----
            bf16x8_t pa[4];
            {
                union { unsigned u[4]; bf16x8_t v; } uu;
#define MK_PA(SV, BASE, OUT)                                     \
                {                                                \
                    unsigned X0 = cvtpk_bf16(SV[BASE + 0], SV[BASE + 1]); \
                    unsigned Y0 = cvtpk_bf16(SV[BASE + 4], SV[BASE + 5]); \
                    pl32swap(X0, Y0);                            \
                    unsigned X1 = cvtpk_bf16(SV[BASE + 2], SV[BASE + 3]); \
                    unsigned Y1 = cvtpk_bf16(SV[BASE + 6], SV[BASE + 7]); \
                    pl32swap(X1, Y1);                            \
                    uu.u[0] = X0; uu.u[1] = X1; uu.u[2] = Y0; uu.u[3] = Y1; \
                    OUT = uu.v;                                  \
                }
                MK_PA(s0, 0, pa[0]);
                MK_PA(s0, 8, pa[1]);
                MK_PA(s1, 0, pa[2]);
                MK_PA(s1, 8, pa[3]);
#undef MK_PA
            }

            // ---- O += P @ V ----
#pragma unroll
            for (int ks = 0; ks < 4; ++ks) {
                bf16x8_t vf[4];
#pragma unroll
                for (int dsub = 0; dsub < 4; ++dsub)
                    vf[dsub] = *(const bf16x8_t*)(Vb + (dsub * 32 + l31) * 128 + ((ks * 32 + hb) ^ swz));
                __builtin_amdgcn_s_setprio(1);
                o0 = __builtin_amdgcn_mfma_f32_32x32x16_bf16(pa[ks], vf[0], o0, 0, 0, 0);
                o1 = __builtin_amdgcn_mfma_f32_32x32x16_bf16(pa[ks], vf[1], o1, 0, 0, 0);
                o2 = __builtin_amdgcn_mfma_f32_32x32x16_bf16(pa[ks], vf[2], o2, 0, 0, 0);
                o3 = __builtin_amdgcn_mfma_f32_32x32x16_bf16(pa[ks], vf[3], o3, 0, 0, 0);
                __builtin_amdgcn_s_setprio(0);
            }
        }
        __syncthreads();
        buf ^= 1;
    }

    // ---- epilogue: normalize by 1/l, store ctx[b][s][h][hd] bf16 ----
    Al[w][l31] = 1.f / l_r;
    unsigned short* cb_ = ctx + (size_t)b * SS * DD + (size_t)h * HDD;
#pragma unroll
    for (int r = 0; r < 16; ++r) {
        const int ql = (r & 3) + 8 * (r >> 2) + 4 * hi;
        float inv = Al[w][ql];
        const size_t rowoff = (size_t)(q0w + ql) * DD;
        cb_[rowoff + 0 * 32 + l31]  = f2bf(o0[r] * inv);
        cb_[rowoff + 1 * 32 + l31]  = f2bf(o1[r] * inv);
        cb_[rowoff + 2 * 32 + l31]  = f2bf(o2[r] * inv);
        cb_[rowoff + 3 * 32 + l31]  = f2bf(o3[r] * inv);
    }
}

extern "C" void kernel_launch(void* const* d_in, const int* in_sizes, int n_in,
                              void* d_out, int out_size, void* d_ws, size_t ws_size,
                              hipStream_t stream) {
    (void)in_sizes; (void)n_in; (void)out_size; (void)ws_size;
    const float* x  = (const float*)d_in[0];
    const float* Wq = (const float*)d_in[1];
    const float* Wk = (const float*)d_in[2];
    const float* Wv = (const float*)d_in[3];
    const float* Wo = (const float*)d_in[4];
    const float* bo = (const float*)d_in[5];

    char* ws = (char*)d_ws;
    unsigned short* xb    = (unsigned short*)(ws);
    unsigned short* WqkvT = (unsigned short*)(ws + (32u << 20));
    unsigned short* WoT   = (unsigned short*)(ws + (56u << 20));
    unsigned short* Qb    = (unsigned short*)(ws + (64u << 20));
    unsigned short* Kb    = (unsigned short*)(ws + (96u << 20));
    unsigned short* Vb    = (unsigned short*)(ws + (128u << 20));
    unsigned short* VTb   = (unsigned short*)(ws + (160u << 20));
    unsigned short* ctx   = xb;  // xb dead after QKV GEMM

    convert_x<<<4096, 256, 0, stream>>>(x, xb, BB * SS * DD);
    transpose_w<<<dim3(64, 64, 4), dim3(32, 8), 0, stream>>>(Wq, Wk, Wv, Wo, WqkvT, WoT);
    gemm_bt<0><<<dim3(48, 64), 256, 0, stream>>>(xb, WqkvT, Qb, Kb, Vb, nullptr, nullptr);
    transpose_v<<<dim3(SS / 32, HDD / 32, BB * HH), dim3(32, 8), 0, stream>>>(Vb, VTb);
    attn_kernel<<<dim3(SS / 256, HH, BB), 512, 0, stream>>>(Qb, Kb, VTb, ctx);
    gemm_bt<1><<<dim3(16, 64), 256, 0, stream>>>(ctx, WoT, nullptr, nullptr, nullptr, (float*)d_out, bo);
}

// Round 4
// 503.940 us; speedup vs baseline: 1.4292x; 1.1767x over previous
//
#include <hip/hip_runtime.h>
#include <hip/hip_bf16.h>

#define BB 4
#define SS 2048
#define DD 2048
#define HH 16
#define HDD 128

typedef __bf16 bf16x8_t __attribute__((ext_vector_type(8)));
typedef float f32x4 __attribute__((ext_vector_type(4)));
typedef float f32x16 __attribute__((ext_vector_type(16)));

static __device__ __forceinline__ unsigned short f2bf(float f) {
    union { float f; unsigned u; } v; v.f = f;
    unsigned r = v.u + 0x7fffu + ((v.u >> 16) & 1u);
    return (unsigned short)(r >> 16);
}

static __device__ __forceinline__ unsigned cvtpk_bf16(float lo, float hiv) {
    unsigned r;
    asm("v_cvt_pk_bf16_f32 %0, %1, %2" : "=v"(r) : "v"(lo), "v"(hiv));
    return r;
}

static __device__ __forceinline__ void pl32swap(unsigned& a, unsigned& b) {
    auto rr = __builtin_amdgcn_permlane32_swap((int)a, (int)b, false, false);
    a = (unsigned)rr[0];
    b = (unsigned)rr[1];
}

static __device__ __forceinline__ void gload_lds16(const void* g, void* lds) {
    __builtin_amdgcn_global_load_lds(
        (const __attribute__((address_space(1))) void*)g,
        (__attribute__((address_space(3))) void*)lds, 16, 0, 0);
}

// ---------------- convert x fp32 -> bf16 ----------------
__global__ void convert_x(const float* __restrict__ x, unsigned short* __restrict__ xb, int n) {
    int i = (blockIdx.x * blockDim.x + threadIdx.x) * 4;
    int stride = gridDim.x * blockDim.x * 4;
    for (; i < n; i += stride) {
        float4 v = *(const float4*)(x + i);
        ushort4 o;
        o.x = f2bf(v.x); o.y = f2bf(v.y); o.z = f2bf(v.z); o.w = f2bf(v.w);
        *(ushort4*)(xb + i) = o;
    }
}

// ---------------- transpose + convert weights: T[n][k] = W[k][n] ----------------
__global__ void transpose_w(const float* __restrict__ Wq, const float* __restrict__ Wk,
                            const float* __restrict__ Wv, const float* __restrict__ Wo,
                            unsigned short* __restrict__ WqkvT, unsigned short* __restrict__ WoT) {
    __shared__ float t[32][33];
    const int z = blockIdx.z;
    const float* W = (z == 0) ? Wq : (z == 1) ? Wk : (z == 2) ? Wv : Wo;
    unsigned short* T = (z < 3) ? (WqkvT + (size_t)z * DD * DD) : WoT;
    const int k0 = blockIdx.x * 32, n0 = blockIdx.y * 32;
    const int tx = threadIdx.x, ty = threadIdx.y;
#pragma unroll
    for (int i = 0; i < 4; ++i) {
        int r = ty + i * 8;
        t[r][tx] = W[(size_t)(k0 + r) * DD + n0 + tx];
    }
    __syncthreads();
#pragma unroll
    for (int i = 0; i < 4; ++i) {
        int r = ty + i * 8;
        T[(size_t)(n0 + r) * DD + k0 + tx] = f2bf(t[tx][r]);
    }
}

// ---------------- 256x256 GEMM, BK=64, 8 waves, counted-vmcnt phase schedule ----------------
// C[M][N] = A[M][2048] * BT[N][2048]^T.
// MODE 0: QKV epilogue (Q,K -> [bh][s][hd] bf16; V -> VT [bh][hd][s] bf16)
// MODE 1: fp32 out + bias
// LDS: A slots [2][256][64] shorts @0, B slots [2][256][64] @65536. XOR-swizzle:
// 16B chunk index c16 ^= (row&7), applied on stage SOURCE and ds_read (involution).
// Stage order per K-tile: B r0,B r1,B r2,B r3, A r0, A r2, A r1, A r3 (idx 0..7).
// Ledger: p0 dsr needs idx<=5 (vmcnt(2)+bar at prev iter end); p1 dsr needs idx6,7
// (vmcnt(8)+bar after p0). Raw s_barrier everywhere: no vmcnt(0) drain in loop.
template <int MODE>
__global__ __launch_bounds__(512, 1) void gemm256(
    const unsigned short* __restrict__ A, const unsigned short* __restrict__ BT,
    unsigned short* __restrict__ outQ, unsigned short* __restrict__ outK,
    unsigned short* __restrict__ outV, float* __restrict__ outF,
    const float* __restrict__ bias) {
    __shared__ __attribute__((aligned(16))) char lds[131072];
    const int tid = threadIdx.x, l = tid & 63;
    const int w = tid >> 6;
    const int wr = w >> 2, wc = w & 3;
    const int nwg = gridDim.x * gridDim.y;
    int lin = blockIdx.y * gridDim.x + blockIdx.x;
    lin = (lin & 7) * (nwg >> 3) + (lin >> 3);
    const int m0 = (lin / gridDim.x) * 256;
    const int n0 = (lin % gridDim.x) * 256;

    f32x4 acc[8][4] = {};

    // ---- staging setup (per-thread: one 16B chunk per region) ----
    const int rowl = tid >> 3, c16s = tid & 7;
    const int sw16 = (c16s ^ (rowl & 7)) * 16;
    const char* aSrc[4];
    const char* bSrc[4];
    // A region order r0,r2,r1,r3 achieved at issue; store plainly here
#pragma unroll
    for (int rg = 0; rg < 4; ++rg) {
        aSrc[rg] = (const char*)A + ((size_t)(m0 + rg * 64 + rowl) * 2048) * 2 + sw16;
        bSrc[rg] = (const char*)BT + ((size_t)(n0 + rg * 64 + rowl) * 2048) * 2 + sw16;
    }
    const int dstOff = tid * 16;

    auto stage = [&](int slot, int off) {
        char* sA = lds + slot * 32768;
        char* sB = lds + 65536 + slot * 32768;
        // B first (idx 0..3)
        gload_lds16(bSrc[0] + off, sB + 0 * 8192 + dstOff);
        gload_lds16(bSrc[1] + off, sB + 1 * 8192 + dstOff);
        gload_lds16(bSrc[2] + off, sB + 2 * 8192 + dstOff);
        gload_lds16(bSrc[3] + off, sB + 3 * 8192 + dstOff);
        // A: r0, r2, r1, r3 (idx 4..7)
        gload_lds16(aSrc[0] + off, sA + 0 * 8192 + dstOff);
        gload_lds16(aSrc[2] + off, sA + 2 * 8192 + dstOff);
        gload_lds16(aSrc[1] + off, sA + 1 * 8192 + dstOff);
        gload_lds16(aSrc[3] + off, sA + 3 * 8192 + dstOff);
    };

    // prologue: tile 0 into slot 0, full drain (one-time)
    stage(0, 0);
    asm volatile("s_waitcnt vmcnt(0)" ::: "memory");
    __builtin_amdgcn_s_barrier();

    const int lr = l & 15, hi4 = l >> 4;
    int cur = 0;
    for (int t = 0; t < 32; ++t) {
        const char* As_ = lds + cur * 32768;
        const char* Bs_ = lds + 65536 + cur * 32768;
        bf16x8_t aa[4], bb[4];
        // ---- p0: dsr A(mh0,kk0) + B(kk0); stage tile t+1; MFMA mh0xkk0 ----
#pragma unroll
        for (int mq = 0; mq < 4; ++mq) {
            int row = wr * 128 + mq * 16 + lr;
            aa[mq] = *(const bf16x8_t*)(As_ + row * 128 + ((hi4) ^ (row & 7)) * 16);
        }
#pragma unroll
        for (int nq = 0; nq < 4; ++nq) {
            int col = wc * 64 + nq * 16 + lr;
            bb[nq] = *(const bf16x8_t*)(Bs_ + col * 128 + ((hi4) ^ (col & 7)) * 16);
        }
        if (t + 1 < 32) stage(cur ^ 1, (t + 1) * 128);
        __builtin_amdgcn_s_setprio(1);
#pragma unroll
        for (int mq = 0; mq < 4; ++mq)
#pragma unroll
            for (int nq = 0; nq < 4; ++nq)
                acc[mq][nq] = __builtin_amdgcn_mfma_f32_16x16x32_bf16(aa[mq], bb[nq], acc[mq][nq], 0, 0, 0);
        __builtin_amdgcn_s_setprio(0);
        if (t + 1 < 32) { asm volatile("s_waitcnt vmcnt(8)" ::: "memory"); }
        else            { asm volatile("s_waitcnt vmcnt(0)" ::: "memory"); }
        __builtin_amdgcn_s_barrier();
        // ---- p1: dsr A(mh1,kk0); MFMA mh1xkk0 (bb kk0 still live) ----
#pragma unroll
        for (int mq = 0; mq < 4; ++mq) {
            int row = wr * 128 + 64 + mq * 16 + lr;
            aa[mq] = *(const bf16x8_t*)(As_ + row * 128 + ((hi4) ^ (row & 7)) * 16);
        }
        __builtin_amdgcn_s_setprio(1);
#pragma unroll
        for (int mq = 0; mq < 4; ++mq)
#pragma unroll
            for (int nq = 0; nq < 4; ++nq)
                acc[4 + mq][nq] = __builtin_amdgcn_mfma_f32_16x16x32_bf16(aa[mq], bb[nq], acc[4 + mq][nq], 0, 0, 0);
        __builtin_amdgcn_s_setprio(0);
        // ---- p2: dsr B(kk1) + A(mh0,kk1); MFMA mh0xkk1 ----
#pragma unroll
        for (int nq = 0; nq < 4; ++nq) {
            int col = wc * 64 + nq * 16 + lr;
            bb[nq] = *(const bf16x8_t*)(Bs_ + col * 128 + ((4 + hi4) ^ (col & 7)) * 16);
        }
#pragma unroll
        for (int mq = 0; mq < 4; ++mq) {
            int row = wr * 128 + mq * 16 + lr;
            aa[mq] = *(const bf16x8_t*)(As_ + row * 128 + ((4 + hi4) ^ (row & 7)) * 16);
        }
        __builtin_amdgcn_s_setprio(1);
#pragma unroll
        for (int mq = 0; mq < 4; ++mq)
#pragma unroll
            for (int nq = 0; nq < 4; ++nq)
                acc[mq][nq] = __builtin_amdgcn_mfma_f32_16x16x32_bf16(aa[mq], bb[nq], acc[mq][nq], 0, 0, 0);
        __builtin_amdgcn_s_setprio(0);
        // ---- p3: dsr A(mh1,kk1); MFMA mh1xkk1; iter-end wait ----
#pragma unroll
        for (int mq = 0; mq < 4; ++mq) {
            int row = wr * 128 + 64 + mq * 16 + lr;
            aa[mq] = *(const bf16x8_t*)(As_ + row * 128 + ((4 + hi4) ^ (row & 7)) * 16);
        }
        __builtin_amdgcn_s_setprio(1);
#pragma unroll
        for (int mq = 0; mq < 4; ++mq)
#pragma unroll
            for (int nq = 0; nq < 4; ++nq)
                acc[4 + mq][nq] = __builtin_amdgcn_mfma_f32_16x16x32_bf16(aa[mq], bb[nq], acc[4 + mq][nq], 0, 0, 0);
        __builtin_amdgcn_s_setprio(0);
        if (t + 1 < 32) { asm volatile("s_waitcnt vmcnt(2)" ::: "memory"); }
        __builtin_amdgcn_s_barrier();
        cur ^= 1;
    }

    // ---- epilogue ----
    const int rbase = m0 + wr * 128 + (hi4 << 2);
    const int cbase = n0 + wc * 64 + lr;
    if (MODE == 0) {
#pragma unroll
        for (int nq = 0; nq < 4; ++nq) {
            int col = cbase + nq * 16;
            int mat = col >> 11;
            int nn = col & 2047;
            int h = nn >> 7, hd = nn & 127;
            if (mat == 2) {
                // V -> VT [bh][hd][s], 4 contiguous s per store
#pragma unroll
                for (int i = 0; i < 8; ++i) {
                    int row = rbase + i * 16;
                    int b = row >> 11, s = row & 2047;
                    ushort4 pk;
                    pk.x = f2bf(acc[i][nq][0]); pk.y = f2bf(acc[i][nq][1]);
                    pk.z = f2bf(acc[i][nq][2]); pk.w = f2bf(acc[i][nq][3]);
                    *(ushort4*)(outV + ((size_t)(b * HH + h) * HDD + hd) * SS + s) = pk;
                }
            } else {
                unsigned short* outp = mat ? outK : outQ;
#pragma unroll
                for (int i = 0; i < 8; ++i) {
#pragma unroll
                    for (int r = 0; r < 4; ++r) {
                        int row = rbase + i * 16 + r;
                        int b = row >> 11, s = row & 2047;
                        outp[((size_t)(b * HH + h) * SS + s) * HDD + hd] = f2bf(acc[i][nq][r]);
                    }
                }
            }
        }
    } else {
#pragma unroll
        for (int nq = 0; nq < 4; ++nq) {
            int col = cbase + nq * 16;
            float bv = bias[col];
#pragma unroll
            for (int i = 0; i < 8; ++i) {
#pragma unroll
                for (int r = 0; r < 4; ++r) {
                    int row = rbase + i * 16 + r;
                    outF[(size_t)row * DD + col] = acc[i][nq][r] + bv;
                }
            }
        }
    }
}

// ---------------- flash attention: 8 warps x 32 q-rows, 32x32 MFMA, swapped QK^T ----------------
__global__ __launch_bounds__(512, 1) void attn_kernel(
    const unsigned short* __restrict__ Q, const unsigned short* __restrict__ K,
    const unsigned short* __restrict__ VT, unsigned short* __restrict__ ctx) {
    __shared__ __attribute__((aligned(16))) unsigned short Ks[2][64 * 128];  // [k=64][d=128]
    __shared__ __attribute__((aligned(16))) unsigned short Vs[2][128 * 64];  // [d=128][k=64]
    __shared__ float Al[8][32];
    const int tid = threadIdx.x, w = tid >> 6, l = tid & 63;
    const int hi = l >> 5, l31 = l & 31;
    const int hb = hi * 16;
    const int swz = (l31 & 7) << 4;
    const int qt = gridDim.x - 1 - blockIdx.x, h = blockIdx.y, b = blockIdx.z;
    const int bh = b * HH + h;
    const int q0w = qt * 256 + w * 32;
    const int qabs = q0w + l31;
    const int nkv = 4 * qt + 4;
    const float scale2 = 0.08838834764831845f * 1.4426950408889634f;

    const unsigned short* Qbh = Q + (size_t)bh * SS * HDD;
    const char* Kbh = (const char*)(K + (size_t)bh * SS * HDD);
    const char* Vbh = (const char*)(VT + (size_t)bh * HDD * SS);

    bf16x8_t qf[8];
#pragma unroll
    for (int ds = 0; ds < 8; ++ds)
        qf[ds] = *(const bf16x8_t*)(Qbh + (size_t)qabs * HDD + ds * 16 + hi * 8);

    const char* kbase[2];
    const char* vbase[2];
#pragma unroll
    for (int iss = 0; iss < 2; ++iss) {
        int p = w * 2048 + iss * 1024 + l * 16;
        int krow = p >> 8, kcb = p & 255;
        kbase[iss] = Kbh + (size_t)krow * 256 + (kcb ^ ((krow & 7) << 4));
        int vrow = p >> 7, vcb = p & 127;
        vbase[iss] = Vbh + (size_t)vrow * (SS * 2) + (vcb ^ ((vrow & 7) << 4));
    }

    auto stage = [&](int buf, int kv0) {
#pragma unroll
        for (int iss = 0; iss < 2; ++iss) {
            gload_lds16(kbase[iss] + (size_t)kv0 * 256, (char*)&Ks[buf][0] + w * 2048 + iss * 1024);
            gload_lds16(vbase[iss] + (size_t)kv0 * 2, (char*)&Vs[buf][0] + w * 2048 + iss * 1024);
        }
    };

    float m_r = -1e30f, l_r = 0.f;
    f32x16 o0 = {}, o1 = {}, o2 = {}, o3 = {};

    int buf = 0;
    stage(0, 0);
    __syncthreads();

    for (int kt = 0; kt < nkv; ++kt) {
        const int kv0 = kt * 64;
        if (kt + 1 < nkv) stage(buf ^ 1, kv0 + 64);

        if (kv0 <= q0w + 31) {
            const char* Kb = (const char*)&Ks[buf][0];
            const char* Vb = (const char*)&Vs[buf][0];
            f32x16 s0 = {}, s1 = {};
            {
                bf16x8_t kf[8];
                const int rb = l31 * 256;
#pragma unroll
                for (int ds = 0; ds < 8; ++ds)
                    kf[ds] = *(const bf16x8_t*)(Kb + rb + ((ds * 32 + hb) ^ swz));
                __builtin_amdgcn_s_setprio(1);
#pragma unroll
                for (int ds = 0; ds < 8; ++ds)
                    s0 = __builtin_amdgcn_mfma_f32_32x32x16_bf16(kf[ds], qf[ds], s0, 0, 0, 0);
                __builtin_amdgcn_s_setprio(0);
#pragma unroll
                for (int ds = 0; ds < 8; ++ds)
                    kf[ds] = *(const bf16x8_t*)(Kb + rb + 32 * 256 + ((ds * 32 + hb) ^ swz));
                __builtin_amdgcn_s_setprio(1);
#pragma unroll
                for (int ds = 0; ds < 8; ++ds)
                    s1 = __builtin_amdgcn_mfma_f32_32x32x16_bf16(kf[ds], qf[ds], s1, 0, 0, 0);
                __builtin_amdgcn_s_setprio(0);
            }

            if (kv0 + 63 > q0w) {
                const int qrel = qabs - kv0;
#pragma unroll
                for (int r = 0; r < 16; ++r) {
                    const int kl = (r & 3) + 8 * (r >> 2) + 4 * hi;
                    s0[r] = (kl > qrel) ? -1e30f : s0[r] * scale2;
                    s1[r] = (kl + 32 > qrel) ? -1e30f : s1[r] * scale2;
                }
            } else {
#pragma unroll
                for (int r = 0; r < 16; ++r) { s0[r] *= scale2; s1[r] *= scale2; }
            }

            float mx = s0[0];
#pragma unroll
            for (int r = 1; r < 16; ++r) mx = fmaxf(mx, s0[r]);
#pragma unroll
            for (int r = 0; r < 16; ++r) mx = fmaxf(mx, s1[r]);
            {
                unsigned mu = __float_as_uint(mx), mu2 = mu;
                pl32swap(mu, mu2);
                mx = fmaxf(__uint_as_float(mu), __uint_as_float(mu2));
            }

            if (__any(mx - m_r > 8.f)) {
                float mnew = fmaxf(m_r, mx);
                float alpha = exp2f(m_r - mnew);
                m_r = mnew;
                l_r *= alpha;
                Al[w][l31] = alpha;
#pragma unroll
                for (int r = 0; r < 16; ++r) {
                    float ar = Al[w][(r & 3) + 8 * (r >> 2) + 4 * hi];
                    o0[r] *= ar; o1[r] *= ar; o2[r] *= ar; o3[r] *= ar;
                }
            }

            float ps = 0.f;
#pragma unroll
            for (int r = 0; r < 16; ++r) { s0[r] = exp2f(s0[r] - m_r); ps += s0[r]; }
#pragma unroll
            for (int r = 0; r < 16; ++r) { s1[r] = exp2f(s1[r] - m_r); ps += s1[r]; }
            {
                unsigned pu = __float_as_uint(ps), pu2 = pu;
                pl32swap(pu, pu2);
                l_r += __uint_as_float(pu) + __uint_as_float(pu2);
            }

            bf16x8_t pa[4];
            {
                union { unsigned u[4]; bf16x8_t v; } uu;
#define MK_PA(SV, BASE, OUT)                                     \
                {                                                \
                    unsigned X0 = cvtpk_bf16(SV[BASE + 0], SV[BASE + 1]); \
                    unsigned Y0 = cvtpk_bf16(SV[BASE + 4], SV[BASE + 5]); \
                    pl32swap(X0, Y0);                            \
                    unsigned X1 = cvtpk_bf16(SV[BASE + 2], SV[BASE + 3]); \
                    unsigned Y1 = cvtpk_bf16(SV[BASE + 6], SV[BASE + 7]); \
                    pl32swap(X1, Y1);                            \
                    uu.u[0] = X0; uu.u[1] = X1; uu.u[2] = Y0; uu.u[3] = Y1; \
                    OUT = uu.v;                                  \
                }
                MK_PA(s0, 0, pa[0]);
                MK_PA(s0, 8, pa[1]);
                MK_PA(s1, 0, pa[2]);
                MK_PA(s1, 8, pa[3]);
#undef MK_PA
            }

#pragma unroll
            for (int ks = 0; ks < 4; ++ks) {
                bf16x8_t vf[4];
#pragma unroll
                for (int dsub = 0; dsub < 4; ++dsub)
                    vf[dsub] = *(const bf16x8_t*)(Vb + (dsub * 32 + l31) * 128 + ((ks * 32 + hb) ^ swz));
                __builtin_amdgcn_s_setprio(1);
                o0 = __builtin_amdgcn_mfma_f32_32x32x16_bf16(pa[ks], vf[0], o0, 0, 0, 0);
                o1 = __builtin_amdgcn_mfma_f32_32x32x16_bf16(pa[ks], vf[1], o1, 0, 0, 0);
                o2 = __builtin_amdgcn_mfma_f32_32x32x16_bf16(pa[ks], vf[2], o2, 0, 0, 0);
                o3 = __builtin_amdgcn_mfma_f32_32x32x16_bf16(pa[ks], vf[3], o3, 0, 0, 0);
                __builtin_amdgcn_s_setprio(0);
            }
        }
        __syncthreads();
        buf ^= 1;
    }

    Al[w][l31] = 1.f / l_r;
    unsigned short* cb_ = ctx + (size_t)b * SS * DD + (size_t)h * HDD;
#pragma unroll
    for (int r = 0; r < 16; ++r) {
        const int ql = (r & 3) + 8 * (r >> 2) + 4 * hi;
        float inv = Al[w][ql];
        const size_t rowoff = (size_t)(q0w + ql) * DD;
        cb_[rowoff + 0 * 32 + l31]  = f2bf(o0[r] * inv);
        cb_[rowoff + 1 * 32 + l31]  = f2bf(o1[r] * inv);
        cb_[rowoff + 2 * 32 + l31]  = f2bf(o2[r] * inv);
        cb_[rowoff + 3 * 32 + l31]  = f2bf(o3[r] * inv);
    }
}

extern "C" void kernel_launch(void* const* d_in, const int* in_sizes, int n_in,
                              void* d_out, int out_size, void* d_ws, size_t ws_size,
                              hipStream_t stream) {
    (void)in_sizes; (void)n_in; (void)out_size; (void)ws_size;
    const float* x  = (const float*)d_in[0];
    const float* Wq = (const float*)d_in[1];
    const float* Wk = (const float*)d_in[2];
    const float* Wv = (const float*)d_in[3];
    const float* Wo = (const float*)d_in[4];
    const float* bo = (const float*)d_in[5];

    char* ws = (char*)d_ws;
    unsigned short* xb    = (unsigned short*)(ws);
    unsigned short* WqkvT = (unsigned short*)(ws + (32u << 20));
    unsigned short* WoT   = (unsigned short*)(ws + (56u << 20));
    unsigned short* Qb    = (unsigned short*)(ws + (64u << 20));
    unsigned short* Kb    = (unsigned short*)(ws + (96u << 20));
    unsigned short* VTb   = (unsigned short*)(ws + (160u << 20));
    unsigned short* ctx   = xb;  // xb dead after QKV GEMM

    convert_x<<<4096, 256, 0, stream>>>(x, xb, BB * SS * DD);
    transpose_w<<<dim3(64, 64, 4), dim3(32, 8), 0, stream>>>(Wq, Wk, Wv, Wo, WqkvT, WoT);
    // QKV fused GEMM: [8192][2048] x [2048][6144]; V written directly transposed
    gemm256<0><<<dim3(24, 32), 512, 0, stream>>>(xb, WqkvT, Qb, Kb, VTb, nullptr, nullptr);
    attn_kernel<<<dim3(SS / 256, HH, BB), 512, 0, stream>>>(Qb, Kb, VTb, ctx);
    gemm256<1><<<dim3(8, 32), 512, 0, stream>>>(ctx, WoT, nullptr, nullptr, nullptr, (float*)d_out, bo);
}

// Round 5
// 426.209 us; speedup vs baseline: 1.6899x; 1.1824x over previous
//
#include <hip/hip_runtime.h>
#include <hip/hip_bf16.h>

#define BB 4
#define SS 2048
#define DD 2048
#define HH 16
#define HDD 128

typedef __bf16 bf16x8_t __attribute__((ext_vector_type(8)));
typedef float f32x4 __attribute__((ext_vector_type(4)));
typedef float f32x16 __attribute__((ext_vector_type(16)));

static __device__ __forceinline__ unsigned short f2bf(float f) {
    union { float f; unsigned u; } v; v.f = f;
    unsigned r = v.u + 0x7fffu + ((v.u >> 16) & 1u);
    return (unsigned short)(r >> 16);
}

static __device__ __forceinline__ unsigned cvtpk_bf16(float lo, float hiv) {
    unsigned r;
    asm("v_cvt_pk_bf16_f32 %0, %1, %2" : "=v"(r) : "v"(lo), "v"(hiv));
    return r;
}

static __device__ __forceinline__ void pl32swap(unsigned& a, unsigned& b) {
    auto rr = __builtin_amdgcn_permlane32_swap((int)a, (int)b, false, false);
    a = (unsigned)rr[0];
    b = (unsigned)rr[1];
}

static __device__ __forceinline__ void gload_lds16(const void* g, void* lds) {
    __builtin_amdgcn_global_load_lds(
        (const __attribute__((address_space(1))) void*)g,
        (__attribute__((address_space(3))) void*)lds, 16, 0, 0);
}

// ---------------- convert x fp32 -> bf16 ----------------
__global__ void convert_x(const float* __restrict__ x, unsigned short* __restrict__ xb, int n) {
    int i = (blockIdx.x * blockDim.x + threadIdx.x) * 4;
    int stride = gridDim.x * blockDim.x * 4;
    for (; i < n; i += stride) {
        float4 v = *(const float4*)(x + i);
        ushort4 o;
        o.x = f2bf(v.x); o.y = f2bf(v.y); o.z = f2bf(v.z); o.w = f2bf(v.w);
        *(ushort4*)(xb + i) = o;
    }
}

// ---------------- transpose + convert weights: T[n][k] = W[k][n] ----------------
__global__ void transpose_w(const float* __restrict__ Wq, const float* __restrict__ Wk,
                            const float* __restrict__ Wv, const float* __restrict__ Wo,
                            unsigned short* __restrict__ WqkvT, unsigned short* __restrict__ WoT) {
    __shared__ float t[32][33];
    const int z = blockIdx.z;
    const float* W = (z == 0) ? Wq : (z == 1) ? Wk : (z == 2) ? Wv : Wo;
    unsigned short* T = (z < 3) ? (WqkvT + (size_t)z * DD * DD) : WoT;
    const int k0 = blockIdx.x * 32, n0 = blockIdx.y * 32;
    const int tx = threadIdx.x, ty = threadIdx.y;
#pragma unroll
    for (int i = 0; i < 4; ++i) {
        int r = ty + i * 8;
        t[r][tx] = W[(size_t)(k0 + r) * DD + n0 + tx];
    }
    __syncthreads();
#pragma unroll
    for (int i = 0; i < 4; ++i) {
        int r = ty + i * 8;
        T[(size_t)(n0 + r) * DD + k0 + tx] = f2bf(t[tx][r]);
    }
}

// ---------------- 256x256 GEMM, BK=64, 8 waves, counted-vmcnt phase schedule ----------------
template <int MODE>
__global__ __launch_bounds__(512, 1) void gemm256(
    const unsigned short* __restrict__ A, const unsigned short* __restrict__ BT,
    unsigned short* __restrict__ outQ, unsigned short* __restrict__ outK,
    unsigned short* __restrict__ outV, float* __restrict__ outF,
    const float* __restrict__ bias) {
    __shared__ __attribute__((aligned(16))) char lds[131072];
    const int tid = threadIdx.x, l = tid & 63;
    const int w = tid >> 6;
    const int wr = w >> 2, wc = w & 3;
    const int nwg = gridDim.x * gridDim.y;
    int lin = blockIdx.y * gridDim.x + blockIdx.x;
    lin = (lin & 7) * (nwg >> 3) + (lin >> 3);
    const int m0 = (lin / gridDim.x) * 256;
    const int n0 = (lin % gridDim.x) * 256;

    f32x4 acc[8][4] = {};

    const int rowl = tid >> 3, c16s = tid & 7;
    const int sw16 = (c16s ^ (rowl & 7)) * 16;
    const char* aSrc[4];
    const char* bSrc[4];
#pragma unroll
    for (int rg = 0; rg < 4; ++rg) {
        aSrc[rg] = (const char*)A + ((size_t)(m0 + rg * 64 + rowl) * 2048) * 2 + sw16;
        bSrc[rg] = (const char*)BT + ((size_t)(n0 + rg * 64 + rowl) * 2048) * 2 + sw16;
    }
    const int dstOff = tid * 16;

    auto stage = [&](int slot, int off) {
        char* sA = lds + slot * 32768;
        char* sB = lds + 65536 + slot * 32768;
        gload_lds16(bSrc[0] + off, sB + 0 * 8192 + dstOff);
        gload_lds16(bSrc[1] + off, sB + 1 * 8192 + dstOff);
        gload_lds16(bSrc[2] + off, sB + 2 * 8192 + dstOff);
        gload_lds16(bSrc[3] + off, sB + 3 * 8192 + dstOff);
        gload_lds16(aSrc[0] + off, sA + 0 * 8192 + dstOff);
        gload_lds16(aSrc[2] + off, sA + 2 * 8192 + dstOff);
        gload_lds16(aSrc[1] + off, sA + 1 * 8192 + dstOff);
        gload_lds16(aSrc[3] + off, sA + 3 * 8192 + dstOff);
    };

    stage(0, 0);
    asm volatile("s_waitcnt vmcnt(0)" ::: "memory");
    __builtin_amdgcn_s_barrier();

    const int lr = l & 15, hi4 = l >> 4;
    int cur = 0;
    for (int t = 0; t < 32; ++t) {
        const char* As_ = lds + cur * 32768;
        const char* Bs_ = lds + 65536 + cur * 32768;
        bf16x8_t aa[4], bb[4];
#pragma unroll
        for (int mq = 0; mq < 4; ++mq) {
            int row = wr * 128 + mq * 16 + lr;
            aa[mq] = *(const bf16x8_t*)(As_ + row * 128 + ((hi4) ^ (row & 7)) * 16);
        }
#pragma unroll
        for (int nq = 0; nq < 4; ++nq) {
            int col = wc * 64 + nq * 16 + lr;
            bb[nq] = *(const bf16x8_t*)(Bs_ + col * 128 + ((hi4) ^ (col & 7)) * 16);
        }
        if (t + 1 < 32) stage(cur ^ 1, (t + 1) * 128);
        __builtin_amdgcn_s_setprio(1);
#pragma unroll
        for (int mq = 0; mq < 4; ++mq)
#pragma unroll
            for (int nq = 0; nq < 4; ++nq)
                acc[mq][nq] = __builtin_amdgcn_mfma_f32_16x16x32_bf16(aa[mq], bb[nq], acc[mq][nq], 0, 0, 0);
        __builtin_amdgcn_s_setprio(0);
        if (t + 1 < 32) { asm volatile("s_waitcnt vmcnt(8)" ::: "memory"); }
        else            { asm volatile("s_waitcnt vmcnt(0)" ::: "memory"); }
        __builtin_amdgcn_s_barrier();
#pragma unroll
        for (int mq = 0; mq < 4; ++mq) {
            int row = wr * 128 + 64 + mq * 16 + lr;
            aa[mq] = *(const bf16x8_t*)(As_ + row * 128 + ((hi4) ^ (row & 7)) * 16);
        }
        __builtin_amdgcn_s_setprio(1);
#pragma unroll
        for (int mq = 0; mq < 4; ++mq)
#pragma unroll
            for (int nq = 0; nq < 4; ++nq)
                acc[4 + mq][nq] = __builtin_amdgcn_mfma_f32_16x16x32_bf16(aa[mq], bb[nq], acc[4 + mq][nq], 0, 0, 0);
        __builtin_amdgcn_s_setprio(0);
#pragma unroll
        for (int nq = 0; nq < 4; ++nq) {
            int col = wc * 64 + nq * 16 + lr;
            bb[nq] = *(const bf16x8_t*)(Bs_ + col * 128 + ((4 + hi4) ^ (col & 7)) * 16);
        }
#pragma unroll
        for (int mq = 0; mq < 4; ++mq) {
            int row = wr * 128 + mq * 16 + lr;
            aa[mq] = *(const bf16x8_t*)(As_ + row * 128 + ((4 + hi4) ^ (row & 7)) * 16);
        }
        __builtin_amdgcn_s_setprio(1);
#pragma unroll
        for (int mq = 0; mq < 4; ++mq)
#pragma unroll
            for (int nq = 0; nq < 4; ++nq)
                acc[mq][nq] = __builtin_amdgcn_mfma_f32_16x16x32_bf16(aa[mq], bb[nq], acc[mq][nq], 0, 0, 0);
        __builtin_amdgcn_s_setprio(0);
#pragma unroll
        for (int mq = 0; mq < 4; ++mq) {
            int row = wr * 128 + 64 + mq * 16 + lr;
            aa[mq] = *(const bf16x8_t*)(As_ + row * 128 + ((4 + hi4) ^ (row & 7)) * 16);
        }
        __builtin_amdgcn_s_setprio(1);
#pragma unroll
        for (int mq = 0; mq < 4; ++mq)
#pragma unroll
            for (int nq = 0; nq < 4; ++nq)
                acc[4 + mq][nq] = __builtin_amdgcn_mfma_f32_16x16x32_bf16(aa[mq], bb[nq], acc[4 + mq][nq], 0, 0, 0);
        __builtin_amdgcn_s_setprio(0);
        if (t + 1 < 32) { asm volatile("s_waitcnt vmcnt(2)" ::: "memory"); }
        __builtin_amdgcn_s_barrier();
        cur ^= 1;
    }

    const int rbase = m0 + wr * 128 + (hi4 << 2);
    const int cbase = n0 + wc * 64 + lr;
    if (MODE == 0) {
#pragma unroll
        for (int nq = 0; nq < 4; ++nq) {
            int col = cbase + nq * 16;
            int mat = col >> 11;
            int nn = col & 2047;
            int h = nn >> 7, hd = nn & 127;
            if (mat == 2) {
#pragma unroll
                for (int i = 0; i < 8; ++i) {
                    int row = rbase + i * 16;
                    int b = row >> 11, s = row & 2047;
                    ushort4 pk;
                    pk.x = f2bf(acc[i][nq][0]); pk.y = f2bf(acc[i][nq][1]);
                    pk.z = f2bf(acc[i][nq][2]); pk.w = f2bf(acc[i][nq][3]);
                    *(ushort4*)(outV + ((size_t)(b * HH + h) * HDD + hd) * SS + s) = pk;
                }
            } else {
                unsigned short* outp = mat ? outK : outQ;
#pragma unroll
                for (int i = 0; i < 8; ++i) {
#pragma unroll
                    for (int r = 0; r < 4; ++r) {
                        int row = rbase + i * 16 + r;
                        int b = row >> 11, s = row & 2047;
                        outp[((size_t)(b * HH + h) * SS + s) * HDD + hd] = f2bf(acc[i][nq][r]);
                    }
                }
            }
        }
    } else {
#pragma unroll
        for (int nq = 0; nq < 4; ++nq) {
            int col = cbase + nq * 16;
            float bv = bias[col];
#pragma unroll
            for (int i = 0; i < 8; ++i) {
#pragma unroll
                for (int r = 0; r < 4; ++r) {
                    int row = rbase + i * 16 + r;
                    outF[(size_t)row * DD + col] = acc[i][nq][r] + bv;
                }
            }
        }
    }
}

// ---------------- flash attention: 4 warps x 32 q-rows, paired q-tiles for uniform blocks ----
// Block p handles q-tile 15-p (heavy) then p (light): 34 KV-tiles per block, all blocks equal.
__global__ __launch_bounds__(256, 2) void attn_kernel(
    const unsigned short* __restrict__ Q, const unsigned short* __restrict__ K,
    const unsigned short* __restrict__ VT, unsigned short* __restrict__ ctx) {
    __shared__ __attribute__((aligned(16))) unsigned short Ks[2][64 * 128];  // [k=64][d=128]
    __shared__ __attribute__((aligned(16))) unsigned short Vs[2][128 * 64];  // [d=128][k=64]
    __shared__ float Al[4][32];
    const int tid = threadIdx.x, w = tid >> 6, l = tid & 63;
    const int hi = l >> 5, l31 = l & 31;
    const int hb = hi * 16;
    const int swz = (l31 & 7) << 4;
    const int p = blockIdx.x, h = blockIdx.y, b = blockIdx.z;
    const int bh = b * HH + h;
    const float scale2 = 0.08838834764831845f * 1.4426950408889634f;

    const unsigned short* Qbh = Q + (size_t)bh * SS * HDD;
    const char* Kbh = (const char*)(K + (size_t)bh * SS * HDD);
    const char* Vbh = (const char*)(VT + (size_t)bh * HDD * SS);

    // staging: 8 chunks of 16B per thread (4 K + 4 V); LDS dest linear, source pre-swizzled
    const char* kbase[4];
    const char* vbase[4];
#pragma unroll
    for (int i = 0; i < 4; ++i) {
        int cp = (i * 256 + tid) * 16;
        int krow = cp >> 8, kcb = cp & 255;
        kbase[i] = Kbh + (size_t)krow * 256 + (kcb ^ ((krow & 7) << 4));
        int vrow = cp >> 7, vcb = cp & 127;
        vbase[i] = Vbh + (size_t)vrow * (SS * 2) + (vcb ^ ((vrow & 7) << 4));
    }

    auto stage = [&](int buf, int kv0) {
#pragma unroll
        for (int i = 0; i < 4; ++i) {
            int cp = (i * 256 + tid) * 16;
            gload_lds16(kbase[i] + (size_t)kv0 * 256, (char*)&Ks[buf][0] + cp);
            gload_lds16(vbase[i] + (size_t)kv0 * 2, (char*)&Vs[buf][0] + cp);
        }
    };

    for (int pass = 0; pass < 2; ++pass) {
        const int qt = pass ? p : 15 - p;
        const int q0w = qt * 128 + w * 32;
        const int qabs = q0w + l31;
        const int nkv = 2 * qt + 2;

        bf16x8_t qf[8];
#pragma unroll
        for (int ds = 0; ds < 8; ++ds)
            qf[ds] = *(const bf16x8_t*)(Qbh + (size_t)qabs * HDD + ds * 16 + hi * 8);

        float m_r = -1e30f, l_r = 0.f;
        f32x16 o0 = {}, o1 = {}, o2 = {}, o3 = {};

        int buf = 0;
        stage(0, 0);
        __syncthreads();

        for (int kt = 0; kt < nkv; ++kt) {
            const int kv0 = kt * 64;
            if (kt + 1 < nkv) stage(buf ^ 1, kv0 + 64);

            if (kv0 <= q0w + 31) {
                const char* Kb = (const char*)&Ks[buf][0];
                const char* Vb = (const char*)&Vs[buf][0];
                f32x16 s0 = {}, s1 = {};
                {
                    bf16x8_t kf[8];
                    const int rb = l31 * 256;
#pragma unroll
                    for (int ds = 0; ds < 8; ++ds)
                        kf[ds] = *(const bf16x8_t*)(Kb + rb + ((ds * 32 + hb) ^ swz));
                    __builtin_amdgcn_s_setprio(1);
#pragma unroll
                    for (int ds = 0; ds < 8; ++ds)
                        s0 = __builtin_amdgcn_mfma_f32_32x32x16_bf16(kf[ds], qf[ds], s0, 0, 0, 0);
                    __builtin_amdgcn_s_setprio(0);
#pragma unroll
                    for (int ds = 0; ds < 8; ++ds)
                        kf[ds] = *(const bf16x8_t*)(Kb + rb + 32 * 256 + ((ds * 32 + hb) ^ swz));
                    __builtin_amdgcn_s_setprio(1);
#pragma unroll
                    for (int ds = 0; ds < 8; ++ds)
                        s1 = __builtin_amdgcn_mfma_f32_32x32x16_bf16(kf[ds], qf[ds], s1, 0, 0, 0);
                    __builtin_amdgcn_s_setprio(0);
                }

                if (kv0 + 63 > q0w) {
                    const int qrel = qabs - kv0;
#pragma unroll
                    for (int r = 0; r < 16; ++r) {
                        const int kl = (r & 3) + 8 * (r >> 2) + 4 * hi;
                        s0[r] = (kl > qrel) ? -1e30f : s0[r] * scale2;
                        s1[r] = (kl + 32 > qrel) ? -1e30f : s1[r] * scale2;
                    }
                } else {
#pragma unroll
                    for (int r = 0; r < 16; ++r) { s0[r] *= scale2; s1[r] *= scale2; }
                }

                float mx = s0[0];
#pragma unroll
                for (int r = 1; r < 16; ++r) mx = fmaxf(mx, s0[r]);
#pragma unroll
                for (int r = 0; r < 16; ++r) mx = fmaxf(mx, s1[r]);
                {
                    unsigned mu = __float_as_uint(mx), mu2 = mu;
                    pl32swap(mu, mu2);
                    mx = fmaxf(__uint_as_float(mu), __uint_as_float(mu2));
                }

                if (__any(mx - m_r > 8.f)) {
                    float mnew = fmaxf(m_r, mx);
                    float alpha = exp2f(m_r - mnew);
                    m_r = mnew;
                    l_r *= alpha;
                    Al[w][l31] = alpha;
#pragma unroll
                    for (int r = 0; r < 16; ++r) {
                        float ar = Al[w][(r & 3) + 8 * (r >> 2) + 4 * hi];
                        o0[r] *= ar; o1[r] *= ar; o2[r] *= ar; o3[r] *= ar;
                    }
                }

                float ps = 0.f;
#pragma unroll
                for (int r = 0; r < 16; ++r) { s0[r] = exp2f(s0[r] - m_r); ps += s0[r]; }
#pragma unroll
                for (int r = 0; r < 16; ++r) { s1[r] = exp2f(s1[r] - m_r); ps += s1[r]; }
                {
                    unsigned pu = __float_as_uint(ps), pu2 = pu;
                    pl32swap(pu, pu2);
                    l_r += __uint_as_float(pu) + __uint_as_float(pu2);
                }

                bf16x8_t pa[4];
                {
                    union { unsigned u[4]; bf16x8_t v; } uu;
#define MK_PA(SV, BASE, OUT)                                     \
                    {                                            \
                        unsigned X0 = cvtpk_bf16(SV[BASE + 0], SV[BASE + 1]); \
                        unsigned Y0 = cvtpk_bf16(SV[BASE + 4], SV[BASE + 5]); \
                        pl32swap(X0, Y0);                        \
                        unsigned X1 = cvtpk_bf16(SV[BASE + 2], SV[BASE + 3]); \
                        unsigned Y1 = cvtpk_bf16(SV[BASE + 6], SV[BASE + 7]); \
                        pl32swap(X1, Y1);                        \
                        uu.u[0] = X0; uu.u[1] = X1; uu.u[2] = Y0; uu.u[3] = Y1; \
                        OUT = uu.v;                              \
                    }
                    MK_PA(s0, 0, pa[0]);
                    MK_PA(s0, 8, pa[1]);
                    MK_PA(s1, 0, pa[2]);
                    MK_PA(s1, 8, pa[3]);
#undef MK_PA
                }

#pragma unroll
                for (int ks = 0; ks < 4; ++ks) {
                    bf16x8_t vf[4];
#pragma unroll
                    for (int dsub = 0; dsub < 4; ++dsub)
                        vf[dsub] = *(const bf16x8_t*)(Vb + (dsub * 32 + l31) * 128 + ((ks * 32 + hb) ^ swz));
                    __builtin_amdgcn_s_setprio(1);
                    o0 = __builtin_amdgcn_mfma_f32_32x32x16_bf16(pa[ks], vf[0], o0, 0, 0, 0);
                    o1 = __builtin_amdgcn_mfma_f32_32x32x16_bf16(pa[ks], vf[1], o1, 0, 0, 0);
                    o2 = __builtin_amdgcn_mfma_f32_32x32x16_bf16(pa[ks], vf[2], o2, 0, 0, 0);
                    o3 = __builtin_amdgcn_mfma_f32_32x32x16_bf16(pa[ks], vf[3], o3, 0, 0, 0);
                    __builtin_amdgcn_s_setprio(0);
                }
            }
            __syncthreads();
            buf ^= 1;
        }

        Al[w][l31] = 1.f / l_r;
        unsigned short* cb_ = ctx + (size_t)b * SS * DD + (size_t)h * HDD;
#pragma unroll
        for (int r = 0; r < 16; ++r) {
            const int ql = (r & 3) + 8 * (r >> 2) + 4 * hi;
            float inv = Al[w][ql];
            const size_t rowoff = (size_t)(q0w + ql) * DD;
            cb_[rowoff + 0 * 32 + l31] = f2bf(o0[r] * inv);
            cb_[rowoff + 1 * 32 + l31] = f2bf(o1[r] * inv);
            cb_[rowoff + 2 * 32 + l31] = f2bf(o2[r] * inv);
            cb_[rowoff + 3 * 32 + l31] = f2bf(o3[r] * inv);
        }
    }
}

extern "C" void kernel_launch(void* const* d_in, const int* in_sizes, int n_in,
                              void* d_out, int out_size, void* d_ws, size_t ws_size,
                              hipStream_t stream) {
    (void)in_sizes; (void)n_in; (void)out_size; (void)ws_size;
    const float* x  = (const float*)d_in[0];
    const float* Wq = (const float*)d_in[1];
    const float* Wk = (const float*)d_in[2];
    const float* Wv = (const float*)d_in[3];
    const float* Wo = (const float*)d_in[4];
    const float* bo = (const float*)d_in[5];

    char* ws = (char*)d_ws;
    unsigned short* xb    = (unsigned short*)(ws);
    unsigned short* WqkvT = (unsigned short*)(ws + (32u << 20));
    unsigned short* WoT   = (unsigned short*)(ws + (56u << 20));
    unsigned short* Qb    = (unsigned short*)(ws + (64u << 20));
    unsigned short* Kb    = (unsigned short*)(ws + (96u << 20));
    unsigned short* VTb   = (unsigned short*)(ws + (160u << 20));
    unsigned short* ctx   = xb;  // xb dead after QKV GEMM

    convert_x<<<4096, 256, 0, stream>>>(x, xb, BB * SS * DD);
    transpose_w<<<dim3(64, 64, 4), dim3(32, 8), 0, stream>>>(Wq, Wk, Wv, Wo, WqkvT, WoT);
    gemm256<0><<<dim3(24, 32), 512, 0, stream>>>(xb, WqkvT, Qb, Kb, VTb, nullptr, nullptr);
    attn_kernel<<<dim3(8, HH, BB), 256, 0, stream>>>(Qb, Kb, VTb, ctx);
    gemm256<1><<<dim3(8, 32), 512, 0, stream>>>(ctx, WoT, nullptr, nullptr, nullptr, (float*)d_out, bo);
}